// Round 13
// baseline (14515.424 us; speedup 1.0000x reference)
//
#include <hip/hip_runtime.h>
#include <math.h>

#define TSTEPS 1024
#define HID    2048
#define IN_D   128
#define OUT_D  128
#define NWG    128
#define NTHR   1024
#define CPW    16          // cells per WG
#define NPAIRS (HID / 2)   // 1024 epoch-tagged 8B words per slot

#define LOG2PI_F 1.8378770664093453f

typedef unsigned long long u64;
typedef unsigned int       u32;

// round-to-nearest-even f32 -> bf16 (low 16 bits)
static __device__ __forceinline__ u32 bf16_rne(float f) {
    u32 u = __float_as_uint(f);
    return (u + 0x7FFFu + ((u >> 16) & 1u)) >> 16;
}
static __device__ __forceinline__ float bf16_lo(u32 payload) {
    return __uint_as_float(payload << 16);
}
static __device__ __forceinline__ float bf16_hi(u32 payload) {
    return __uint_as_float(payload & 0xFFFF0000u);
}
// fast transcendentals (v_exp_f32 + v_rcp_f32; ~1e-7 rel err vs 0.21 threshold)
static __device__ __forceinline__ float fast_sig(float x) {
    return __builtin_amdgcn_rcpf(1.0f + __expf(-x));
}
static __device__ __forceinline__ float fast_tanh(float x) {
    return 1.0f - 2.0f * __builtin_amdgcn_rcpf(1.0f + __expf(2.0f * x));
}

// ---------------------------------------------------------------------------
// Persistent LSTM rollout — fewer-sync-domains probe, spill-free.
// 128 WGs x 1024 threads (16 waves). Wave rg owns cell 16w+rg completely
// (rows m*2048+cell, m=0..3); per-THREAD shape identical to round 12:
// 128 f32 W_hh in registers, 4 accumulators, 64-lane butterfly.
//
// vs r12, the sync-domain metrics all shrink:
//   * consumers: 128 (straggler population halved)
//   * poll sweep: 128 WGs x 8KB = 1MB/iteration (halved)
//   * detect quantum: ONE pair per lane (minimum poll loop)
//   * publish: 8 x u64 from 8 lanes of wave 0 = one 64B line (+64B hs line)
//
// Protocol unchanged (r6/r10 lineage): u64 pair = tag32 | 2 x bf16 h, slot
// parity double buffer, relaxed agent-scope (L3) atomics only, exact-match
// tags. Skew-safety induction identical: a WG publishes tag t+2 (overwriting
// tag t, same parity) only after all its waves consumed tag t+1 from ALL
// WGs, which required every WG to have published t+1, which required every
// WG's waves to have consumed tag t.
// ---------------------------------------------------------------------------
__global__ __launch_bounds__(NTHR)
void lstm_persist(const float* __restrict__ s0,
                  const float* __restrict__ Wih,
                  const float* __restrict__ Whh,
                  const float* __restrict__ bih,
                  const float* __restrict__ bhh,
                  float* __restrict__ hs_out,
                  u64* __restrict__ pairs)     // [2][NPAIRS]
{
    __shared__ __align__(16) float4 ldsH[2][HID / 4];  // staged h, swizzled
    __shared__ __align__(16) u64    cellbuf[CPW];      // [wave]: lo=f32 h, hi=bf16 h

    const int tid   = threadIdx.x;
    const int wg    = blockIdx.x;
    const int hbase = wg * CPW;
    const int rg    = tid >> 6;    // wave id 0..15
    const int lane  = tid & 63;
    const int cell  = hbase + rg;  // this wave's cell

    // ---- weights -> registers: rows m*2048+cell, k-slice [32*lane, +32) ----
    float w[4][32];
    float wih2[4][2];
    float breg[4];
#pragma unroll
    for (int m = 0; m < 4; ++m) {
        const int grow = m * HID + cell;
        const float4* src = (const float4*)(Whh + (size_t)grow * HID + lane * 32);
#pragma unroll
        for (int q = 0; q < 8; ++q) {
            float4 v = src[q];
            w[m][4*q+0] = v.x; w[m][4*q+1] = v.y;
            w[m][4*q+2] = v.z; w[m][4*q+3] = v.w;
        }
        wih2[m][0] = Wih[(size_t)grow * IN_D + 2 * lane];
        wih2[m][1] = Wih[(size_t)grow * IN_D + 2 * lane + 1];
        breg[m]    = bih[grow] + bhh[grow];
    }

    float c = 0.0f;   // cell state (lane 0 of each wave)

    for (int t = 0; t < TSTEPS; ++t) {
        const int slot = (t - 1) & 1;   // consumed slot (valid when t > 0)

        // ---- W_ih @ x_t partial (no h dependency) ----
        const float2 xv = *(const float2*)(s0 + (size_t)t * IN_D + 2 * lane);
        float acc[4];
#pragma unroll
        for (int m = 0; m < 4; ++m)
            acc[m] = wih2[m][0] * xv.x + wih2[m][1] * xv.y;

        // ---- per-wave collective detect + stage: wave rg owns 64 pairs ----
        if (t > 0) {
            const u32 want = (u32)t;
            const int idx  = rg * 64 + lane;            // pair index 0..1023
            const u64* sp  = pairs + (size_t)slot * NPAIRS + idx;
            u64 q0;
            for (;;) {
                q0 = __hip_atomic_load(sp, __ATOMIC_RELAXED, __HIP_MEMORY_SCOPE_AGENT);
                if (__all((u32)(q0 >> 32) == want)) break;
                __builtin_amdgcn_s_sleep(1);
            }
            // unpack 1 pair -> 2 f32, one b64 write, swizzled 16B-chunk layout
            const int cch = idx >> 1;                   // 16B chunk 0..511
            const int p   = cch ^ ((cch >> 3) & 7);
            ((float2*)&ldsH[slot][p])[idx & 1] =
                make_float2(bf16_lo((u32)q0), bf16_hi((u32)q0));
        }
        __syncthreads();   // sync1: ldsH staged

        // ---- recurrent matvec: 4 rows x 32 k per thread ----
        if (t > 0) {
#pragma unroll
            for (int j = 0; j < 8; ++j) {
                const int p = (8 * lane + j) ^ (lane & 7);
                float4 hv = ldsH[slot][p];
#pragma unroll
                for (int m = 0; m < 4; ++m) {
                    acc[m] += hv.x * w[m][4*j+0];
                    acc[m] += hv.y * w[m][4*j+1];
                    acc[m] += hv.z * w[m][4*j+2];
                    acc[m] += hv.w * w[m][4*j+3];
                }
            }
        }

        // ---- full 64-lane butterfly: all 4 gate sums complete at lane 0 ----
#pragma unroll
        for (int m = 0; m < 4; ++m) {
            acc[m] += __shfl_xor(acc[m], 1);
            acc[m] += __shfl_xor(acc[m], 2);
            acc[m] += __shfl_xor(acc[m], 4);
            acc[m] += __shfl_xor(acc[m], 8);
            acc[m] += __shfl_xor(acc[m], 16);
            acc[m] += __shfl_xor(acc[m], 32);
        }

        // ---- in-wave cell update (parallel across 16 waves, pre-sync2) ----
        if (lane == 0) {
            const float ig = fast_sig (acc[0] + breg[0]);
            const float fg = fast_sig (acc[1] + breg[1]);
            const float gg = fast_tanh(acc[2] + breg[2]);
            const float og = fast_sig (acc[3] + breg[3]);
            c = fg * c + ig * gg;
            const float h = og * fast_tanh(c);
            cellbuf[rg] = ((u64)bf16_rne(h) << 32) | (u64)__float_as_uint(h);
        }
        __syncthreads();   // sync2: cellbuf ready

        // ---- pack + publish (threads 0..7 of wave 0; one 64B line each way) ----
        if (tid < 8) {
            const u64 cb0 = cellbuf[2 * tid];
            const u64 cb1 = cellbuf[2 * tid + 1];
            const u64 pair = (((u64)(u32)(t + 1)) << 32)
                           | (u64)(((u32)(cb0 >> 32)) | (((u32)(cb1 >> 32)) << 16));
            __hip_atomic_store(&pairs[(size_t)(t & 1) * NPAIRS + wg * 8 + tid], pair,
                               __ATOMIC_RELAXED, __HIP_MEMORY_SCOPE_AGENT);
            // f32 record for out_head: 8 lanes x float2 = 64B coalesced
            *(float2*)&hs_out[(size_t)t * HID + hbase + 2 * tid] =
                make_float2(__uint_as_float((u32)cb0), __uint_as_float((u32)cb1));
        }
    }
}

// ---------------------------------------------------------------------------
// Output head: mu/logvar GEMV + sample + logprob. Block = 4 timesteps.
// ---------------------------------------------------------------------------
__global__ __launch_bounds__(256)
void out_head(const float* __restrict__ eps,
              const float* __restrict__ Wmu,
              const float* __restrict__ bmu,
              const float* __restrict__ Wlv,
              const float* __restrict__ blv,
              const float* __restrict__ hs,
              float* __restrict__ xs,
              float* __restrict__ lp)
{
    __shared__ __align__(16) float hlds[4][HID];
    __shared__ __align__(16) float exch[4][256];

    const int tid = threadIdx.x;
    const int t0  = blockIdx.x * 4;

    {
        const float4* src = (const float4*)(hs + (size_t)t0 * HID);
        float4* dst = (float4*)&hlds[0][0];
#pragma unroll
        for (int i = 0; i < 8; ++i)
            dst[tid + i * 256] = src[tid + i * 256];
    }
    __syncthreads();

    const int  jrow  = tid & 127;
    const bool is_lv = tid >= 128;
    const float* Wrow = (is_lv ? Wlv : Wmu) + (size_t)jrow * HID;
    const float  bias = is_lv ? blv[jrow] : bmu[jrow];

    float acc[4] = {0.f, 0.f, 0.f, 0.f};
    const float4* w4 = (const float4*)Wrow;
#pragma unroll 4
    for (int kq = 0; kq < HID / 4; ++kq) {
        float4 wv = w4[kq];
#pragma unroll
        for (int tt = 0; tt < 4; ++tt) {
            float4 hv = ((const float4*)&hlds[tt][0])[kq];
            acc[tt] += wv.x * hv.x + wv.y * hv.y + wv.z * hv.z + wv.w * hv.w;
        }
    }
#pragma unroll
    for (int tt = 0; tt < 4; ++tt) exch[tt][tid] = acc[tt] + bias;
    __syncthreads();

#pragma unroll
    for (int r = 0; r < 2; ++r) {
        const int item = tid + r * 256;
        const int tt = item >> 7;
        const int jj = item & 127;
        const int t  = t0 + tt;
        const float mu = exch[tt][jj];
        const float lv = exch[tt][128 + jj];
        const float e  = eps[(size_t)t * OUT_D + jj];
        const float sd = expf(0.5f * lv);
        const float x  = mu + sd * e;
        const float d  = (x - mu) / sd;
        const float l  = -0.5f * d * d - 0.5f * lv - 0.5f * LOG2PI_F;
        xs[(size_t)t * OUT_D + jj] = x;
        lp[(size_t)t * OUT_D + jj] = l;
    }
}

// ---------------------------------------------------------------------------
extern "C" void kernel_launch(void* const* d_in, const int* in_sizes, int n_in,
                              void* d_out, int out_size, void* d_ws, size_t ws_size,
                              hipStream_t stream)
{
    (void)in_sizes; (void)n_in; (void)out_size; (void)ws_size;

    const float* s0  = (const float*)d_in[0];
    const float* eps = (const float*)d_in[1];
    const float* Wih = (const float*)d_in[2];
    const float* Whh = (const float*)d_in[3];
    const float* bih = (const float*)d_in[4];
    const float* bhh = (const float*)d_in[5];
    const float* Wmu = (const float*)d_in[6];
    const float* bmu = (const float*)d_in[7];
    const float* Wlv = (const float*)d_in[8];
    const float* blv = (const float*)d_in[9];

    float* out = (float*)d_out;
    float* xs = out;                         // [1024][128]
    float* lp = out + TSTEPS * OUT_D;        // [1024][128]
    float* hs = out + 2 * TSTEPS * OUT_D;    // [1024][2048]

    u64* pairs = (u64*)d_ws;                 // [2][1024] x 8B = 16KB

    // zero tags each launch (tag 0 matches no wanted tag >= 1)
    (void)hipMemsetAsync(d_ws, 0, 2 * NPAIRS * sizeof(u64), stream);

    hipLaunchKernelGGL(lstm_persist, dim3(NWG), dim3(NTHR), 0, stream,
                       s0, Wih, Whh, bih, bhh, hs, pairs);

    hipLaunchKernelGGL(out_head, dim3(TSTEPS / 4), dim3(256), 0, stream,
                       eps, Wmu, bmu, Wlv, blv, hs, xs, lp);
}

// Round 14
// 3716.001 us; speedup vs baseline: 3.9062x; 3.9062x over previous
//
#include <hip/hip_runtime.h>
#include <math.h>

#define TSTEPS 1024
#define HID    2048
#define IN_D   128
#define OUT_D  128
#define NWG    256
#define NTHR   512
#define NPAIRS (HID / 2)   // 1024 epoch-tagged 8B words per slot

#define LOG2PI_F 1.8378770664093453f

typedef unsigned long long u64;
typedef unsigned int       u32;

// round-to-nearest-even f32 -> bf16 (low 16 bits)
static __device__ __forceinline__ u32 bf16_rne(float f) {
    u32 u = __float_as_uint(f);
    return (u + 0x7FFFu + ((u >> 16) & 1u)) >> 16;
}
static __device__ __forceinline__ float bf16_lo(u32 payload) {   // bits 0..15
    return __uint_as_float(payload << 16);
}
static __device__ __forceinline__ float bf16_hi(u32 payload) {   // bits 16..31
    return __uint_as_float(payload & 0xFFFF0000u);
}
// fast transcendentals (v_exp_f32 + v_rcp_f32; ~1e-7 rel err vs 0.21 threshold)
static __device__ __forceinline__ float fast_sig(float x) {
    return __builtin_amdgcn_rcpf(1.0f + __expf(-x));
}
static __device__ __forceinline__ float fast_tanh(float x) {
    return 1.0f - 2.0f * __builtin_amdgcn_rcpf(1.0f + __expf(2.0f * x));
}

// ---------------------------------------------------------------------------
// Persistent LSTM rollout — k-major, self-polled, no LDS h-exchange.
// 256 WGs x 512 thr. Thread (rg, H=lane>>5, sl=lane&31):
//   rows  li in [16H, 16H+16)   (row(li) = (li>>3)*2048 + 8*wg + (li&7))
//   k     cells [256rg + 8sl, +8)  == pairs [128rg + 4sl, +4)
// The thread's 8 h-values are exactly the 4 pairs it polls itself ->
// NO ldsH, NO sync1. Wave rg's wait-set = producers [32rg, 32rg+32) only.
// Reduction: fold-butterfly (reduce-scatter) within each 32-lane half:
// masks 1,2,4,8 halve live accs 16->1 (lane keeps upper half iff lane&m),
// then xor-16 completes. Lane (b4=0) holds row 16H + brev4(sl&15); deposits
// to gpart[par][rg][li] (parity-double-buffered). One syncthreads; wave 0
// combines 8 partials + bias, shuffles gates together, 8-lane cell update,
// then 4 even lanes publish 4 contiguous u64 (32B) + 8 lanes write 32B hs.
//
// Overwrite safety (per-wave progress): slot s=par(tau) gets tag tau+1 at
// iter tau and tag tau+3 at iter tau+2. Any WG writes tag tau+3 only after
// its waves consumed tag tau+2, which needs ALL WGs to have published
// tau+2, which needs each WG's syncthreads(tau+1), which needs all its
// waves' deposits at tau+1, which needs their consume of tag tau+1 from
// slot s. So tag tau+1 is consumed everywhere before any overwrite.
// gpart parity: deposit(t+2) (same parity as t) requires poll(tag t+2)
// success -> all WGs combined at t+1 -> this WG's wave 0 long past
// combine(t)'s gpart reads.
// ---------------------------------------------------------------------------
__global__ __launch_bounds__(NTHR, 2)
void lstm_persist(const float* __restrict__ s0,
                  const float* __restrict__ Wih,
                  const float* __restrict__ Whh,
                  const float* __restrict__ bih,
                  const float* __restrict__ bhh,
                  float* __restrict__ hs_out,
                  u64* __restrict__ pairs)     // [2][NPAIRS]
{
    __shared__ __align__(16) float gpart[2][8][32];

    const int tid   = threadIdx.x;
    const int wg    = blockIdx.x;
    const int hbase = wg * 8;
    const int rg    = tid >> 6;    // wave id 0..7
    const int lane  = tid & 63;
    const int H     = lane >> 5;   // row half 0/1
    const int sl    = lane & 31;   // k sublane

    // ---- W_hh -> registers: 16 rows x 8 k ----
    float w[16][8];
    const int k0 = 256 * rg + 8 * sl;
#pragma unroll
    for (int r = 0; r < 16; ++r) {
        const int li   = 16 * H + r;
        const int grow = (li >> 3) * HID + hbase + (li & 7);
        const float4* src = (const float4*)(Whh + (size_t)grow * HID + k0);
        float4 a = src[0], b = src[1];
        w[r][0] = a.x; w[r][1] = a.y; w[r][2] = a.z; w[r][3] = a.w;
        w[r][4] = b.x; w[r][5] = b.y; w[r][6] = b.z; w[r][7] = b.w;
    }
    // ---- W_ih: lanes sl<16 own x-k = 16rg + sl for their 16 rows ----
    float wihr[16];
    const int xk = 16 * rg + sl;
#pragma unroll
    for (int r = 0; r < 16; ++r) wihr[r] = 0.f;
    if (sl < 16) {
#pragma unroll
        for (int r = 0; r < 16; ++r) {
            const int li   = 16 * H + r;
            const int grow = (li >> 3) * HID + hbase + (li & 7);
            wihr[r] = Wih[(size_t)grow * IN_D + xk];
        }
    }
    // ---- bias for combine (wave 0, lanes<32: row = lane) ----
    float breg = 0.f;
    if (rg == 0 && lane < 32) {
        const int grow = (lane >> 3) * HID + hbase + (lane & 7);
        breg = bih[grow] + bhh[grow];
    }

    float c = 0.0f;   // cell state: wave 0, lanes 0..7

    for (int t = 0; t < TSTEPS; ++t) {
        // ---- W_ih @ x_t partial (no h dependency) ----
        const float xv = (sl < 16) ? s0[(size_t)t * IN_D + xk] : 0.f;
        float acc[16];
#pragma unroll
        for (int r = 0; r < 16; ++r) acc[r] = wihr[r] * xv;

        // ---- self-poll own 4 pairs of h(t-1), then matvec ----
        if (t > 0) {
            const u32 want = (u32)t;
            const u64* sp = pairs + (size_t)((t - 1) & 1) * NPAIRS + 128 * rg + 4 * sl;
            u64 q0, q1, q2, q3;
            for (;;) {
                q0 = __hip_atomic_load(sp + 0, __ATOMIC_RELAXED, __HIP_MEMORY_SCOPE_AGENT);
                q1 = __hip_atomic_load(sp + 1, __ATOMIC_RELAXED, __HIP_MEMORY_SCOPE_AGENT);
                q2 = __hip_atomic_load(sp + 2, __ATOMIC_RELAXED, __HIP_MEMORY_SCOPE_AGENT);
                q3 = __hip_atomic_load(sp + 3, __ATOMIC_RELAXED, __HIP_MEMORY_SCOPE_AGENT);
                const int ok = ((u32)(q0 >> 32) == want) & ((u32)(q1 >> 32) == want)
                             & ((u32)(q2 >> 32) == want) & ((u32)(q3 >> 32) == want);
                if (__all(ok)) break;
                __builtin_amdgcn_s_sleep(1);
            }
            const float h0 = bf16_lo((u32)q0), h1 = bf16_hi((u32)q0);
            const float h2 = bf16_lo((u32)q1), h3 = bf16_hi((u32)q1);
            const float h4 = bf16_lo((u32)q2), h5 = bf16_hi((u32)q2);
            const float h6 = bf16_lo((u32)q3), h7 = bf16_hi((u32)q3);
#pragma unroll
            for (int r = 0; r < 16; ++r) {
                acc[r] += h0 * w[r][0] + h1 * w[r][1] + h2 * w[r][2] + h3 * w[r][3]
                        + h4 * w[r][4] + h5 * w[r][5] + h6 * w[r][6] + h7 * w[r][7];
            }
        }

        // ---- fold butterfly (reduce-scatter) within each 32-lane half ----
        {
            const bool u1 = lane & 1;
#pragma unroll
            for (int i = 0; i < 8; ++i) {
                const float send = u1 ? acc[i] : acc[i + 8];
                const float recv = __shfl_xor(send, 1);
                acc[i] = (u1 ? acc[i + 8] : acc[i]) + recv;
            }
            const bool u2 = lane & 2;
#pragma unroll
            for (int i = 0; i < 4; ++i) {
                const float send = u2 ? acc[i] : acc[i + 4];
                const float recv = __shfl_xor(send, 2);
                acc[i] = (u2 ? acc[i + 4] : acc[i]) + recv;
            }
            const bool u4 = lane & 4;
#pragma unroll
            for (int i = 0; i < 2; ++i) {
                const float send = u4 ? acc[i] : acc[i + 2];
                const float recv = __shfl_xor(send, 4);
                acc[i] = (u4 ? acc[i + 2] : acc[i]) + recv;
            }
            const bool u8 = lane & 8;
            {
                const float send = u8 ? acc[0] : acc[1];
                const float recv = __shfl_xor(send, 8);
                acc[0] = (u8 ? acc[1] : acc[0]) + recv;
            }
            acc[0] += __shfl_xor(acc[0], 16);
        }

        // ---- deposit per-wave row partials (parity double buffer) ----
        const int par = t & 1;
        if ((lane & 16) == 0) {
            const int sb    = lane & 15;
            const int rstar = ((sb & 1) << 3) | ((sb & 2) << 1)
                            | ((sb & 4) >> 1) | ((sb & 8) >> 3);   // brev4
            gpart[par][rg][16 * H + rstar] = acc[0];
        }
        __syncthreads();   // the ONLY barrier per step

        // ---- combine + cell update + publish (wave 0) ----
        if (rg == 0) {
            float g = 0.f;
            if (lane < 32) {
                g = breg;
#pragma unroll
                for (int k = 0; k < 8; ++k) g += gpart[par][k][lane];
            }
            const int j = lane & 7;
            const float zi = __shfl(g, j);
            const float zf = __shfl(g, j + 8);
            const float zg = __shfl(g, j + 16);
            const float zo = __shfl(g, j + 24);
            float h = 0.f;
            if (lane < 8) {
                const float ig = fast_sig(zi);
                const float fg = fast_sig(zf);
                const float gg = fast_tanh(zg);
                const float og = fast_sig(zo);
                c = fg * c + ig * gg;
                h = og * fast_tanh(c);
                hs_out[(size_t)t * HID + hbase + lane] = h;   // 8 x 4B = 32B line
            }
            const float ho = __shfl_xor(h, 1);
            if (lane < 8 && (lane & 1) == 0) {
                const u64 pair = (((u64)(u32)(t + 1)) << 32)
                               | (u64)(bf16_rne(h) | (bf16_rne(ho) << 16));
                __hip_atomic_store(&pairs[(size_t)(t & 1) * NPAIRS + wg * 4 + (lane >> 1)],
                                   pair, __ATOMIC_RELAXED, __HIP_MEMORY_SCOPE_AGENT);
            }
        }
    }
}

// ---------------------------------------------------------------------------
// Output head: mu/logvar GEMV + sample + logprob. Block = 4 timesteps.
// ---------------------------------------------------------------------------
__global__ __launch_bounds__(256)
void out_head(const float* __restrict__ eps,
              const float* __restrict__ Wmu,
              const float* __restrict__ bmu,
              const float* __restrict__ Wlv,
              const float* __restrict__ blv,
              const float* __restrict__ hs,
              float* __restrict__ xs,
              float* __restrict__ lp)
{
    __shared__ __align__(16) float hlds[4][HID];
    __shared__ __align__(16) float exch[4][256];

    const int tid = threadIdx.x;
    const int t0  = blockIdx.x * 4;

    {
        const float4* src = (const float4*)(hs + (size_t)t0 * HID);
        float4* dst = (float4*)&hlds[0][0];
#pragma unroll
        for (int i = 0; i < 8; ++i)
            dst[tid + i * 256] = src[tid + i * 256];
    }
    __syncthreads();

    const int  jrow  = tid & 127;
    const bool is_lv = tid >= 128;
    const float* Wrow = (is_lv ? Wlv : Wmu) + (size_t)jrow * HID;
    const float  bias = is_lv ? blv[jrow] : bmu[jrow];

    float acc[4] = {0.f, 0.f, 0.f, 0.f};
    const float4* w4 = (const float4*)Wrow;
#pragma unroll 4
    for (int kq = 0; kq < HID / 4; ++kq) {
        float4 wv = w4[kq];
#pragma unroll
        for (int tt = 0; tt < 4; ++tt) {
            float4 hv = ((const float4*)&hlds[tt][0])[kq];
            acc[tt] += wv.x * hv.x + wv.y * hv.y + wv.z * hv.z + wv.w * hv.w;
        }
    }
#pragma unroll
    for (int tt = 0; tt < 4; ++tt) exch[tt][tid] = acc[tt] + bias;
    __syncthreads();

#pragma unroll
    for (int r = 0; r < 2; ++r) {
        const int item = tid + r * 256;
        const int tt = item >> 7;
        const int jj = item & 127;
        const int t  = t0 + tt;
        const float mu = exch[tt][jj];
        const float lv = exch[tt][128 + jj];
        const float e  = eps[(size_t)t * OUT_D + jj];
        const float sd = expf(0.5f * lv);
        const float x  = mu + sd * e;
        const float d  = (x - mu) / sd;
        const float l  = -0.5f * d * d - 0.5f * lv - 0.5f * LOG2PI_F;
        xs[(size_t)t * OUT_D + jj] = x;
        lp[(size_t)t * OUT_D + jj] = l;
    }
}

// ---------------------------------------------------------------------------
extern "C" void kernel_launch(void* const* d_in, const int* in_sizes, int n_in,
                              void* d_out, int out_size, void* d_ws, size_t ws_size,
                              hipStream_t stream)
{
    (void)in_sizes; (void)n_in; (void)out_size; (void)ws_size;

    const float* s0  = (const float*)d_in[0];
    const float* eps = (const float*)d_in[1];
    const float* Wih = (const float*)d_in[2];
    const float* Whh = (const float*)d_in[3];
    const float* bih = (const float*)d_in[4];
    const float* bhh = (const float*)d_in[5];
    const float* Wmu = (const float*)d_in[6];
    const float* bmu = (const float*)d_in[7];
    const float* Wlv = (const float*)d_in[8];
    const float* blv = (const float*)d_in[9];

    float* out = (float*)d_out;
    float* xs = out;                         // [1024][128]
    float* lp = out + TSTEPS * OUT_D;        // [1024][128]
    float* hs = out + 2 * TSTEPS * OUT_D;    // [1024][2048]

    u64* pairs = (u64*)d_ws;                 // [2][1024] x 8B = 16KB

    // zero tags each launch (tag 0 matches no wanted tag >= 1)
    (void)hipMemsetAsync(d_ws, 0, 2 * NPAIRS * sizeof(u64), stream);

    hipLaunchKernelGGL(lstm_persist, dim3(NWG), dim3(NTHR), 0, stream,
                       s0, Wih, Whh, bih, bhh, hs, pairs);

    hipLaunchKernelGGL(out_head, dim3(TSTEPS / 4), dim3(256), 0, stream,
                       eps, Wmu, bmu, Wlv, blv, hs, xs, lp);
}

// Round 15
// 2962.625 us; speedup vs baseline: 4.8995x; 1.2543x over previous
//
#include <hip/hip_runtime.h>
#include <math.h>

#define TSTEPS 1024
#define HID    2048
#define IN_D   128
#define OUT_D  128
#define NWG    256
#define NTHR   512
#define NPAIRS (HID / 2)   // 1024 epoch-tagged 8B words per slot

#define LOG2PI_F 1.8378770664093453f

typedef unsigned long long u64;
typedef unsigned int       u32;

// round-to-nearest-even f32 -> bf16 (low 16 bits)
static __device__ __forceinline__ u32 bf16_rne(float f) {
    u32 u = __float_as_uint(f);
    return (u + 0x7FFFu + ((u >> 16) & 1u)) >> 16;
}
static __device__ __forceinline__ float bf16_lo(u32 payload) {
    return __uint_as_float(payload << 16);
}
static __device__ __forceinline__ float bf16_hi(u32 payload) {
    return __uint_as_float(payload & 0xFFFF0000u);
}
// fast transcendentals (v_exp_f32 + v_rcp_f32; ~1e-7 rel err vs 0.21 threshold)
static __device__ __forceinline__ float fast_sig(float x) {
    return __builtin_amdgcn_rcpf(1.0f + __expf(-x));
}
static __device__ __forceinline__ float fast_tanh(float x) {
    return 1.0f - 2.0f * __builtin_amdgcn_rcpf(1.0f + __expf(2.0f * x));
}

// ---------------------------------------------------------------------------
// Persistent LSTM rollout — r12 structure (best measured: 2947 us), with the
// poll loop's s_sleep removed (hard spin: check-then-reload, period = load
// RTT, no sleep-quantum added to every discovery's max-over-waves).
//
//  * 256 WGs x 512 thr; wave rg owns cell 8w+rg (rows m*2048+cell);
//    128 f32 W_hh in registers per thread (VGPR ~108, no spill).
//  * u64 pair = tag32 | 2 x bf16 h; slot-parity double buffer; relaxed
//    agent-scope (L3-coherent) atomics only; exact-match tags.
//  * detection split 8 ways: every wave polls its own 128-pair slice
//    (2 pairs = 16B per lane), exits on __all(2 tags match), stages f32
//    into swizzled ldsH with one b128 write per lane.
//  * producer tail: in-wave cell update on lane 0 (pre-sync2), then wave-0
//    threads 0..3 pack + publish 4 contiguous u64 (32B burst) + 32B f32
//    hs_out line. No scattered 4B stores.
//
// Skew safety (r6 induction): a WG publishes tag t+2 (overwriting tag t,
// same parity slot) only after all its waves consumed tag t+1 from ALL WGs,
// which required every WG to have published t+1, which required every WG's
// waves to have consumed tag t.
// ---------------------------------------------------------------------------
__global__ __launch_bounds__(NTHR)
void lstm_persist(const float* __restrict__ s0,
                  const float* __restrict__ Wih,
                  const float* __restrict__ Whh,
                  const float* __restrict__ bih,
                  const float* __restrict__ bhh,
                  float* __restrict__ hs_out,
                  u64* __restrict__ pairs)     // [2][NPAIRS]
{
    __shared__ __align__(16) float4 ldsH[2][HID / 4];  // staged h, swizzled
    __shared__ __align__(16) u64    cellbuf[8];        // [wave]: lo=f32 h, hi=bf16 h

    const int tid   = threadIdx.x;
    const int wg    = blockIdx.x;
    const int hbase = wg * 8;
    const int rg    = tid >> 6;    // wave id 0..7
    const int lane  = tid & 63;
    const int cell  = hbase + rg;  // this wave's cell

    // ---- weights -> registers: rows m*2048+cell, k-slice [32*lane, +32) ----
    float w[4][32];
    float wih2[4][2];
    float breg[4];
#pragma unroll
    for (int m = 0; m < 4; ++m) {
        const int grow = m * HID + cell;
        const float4* src = (const float4*)(Whh + (size_t)grow * HID + lane * 32);
#pragma unroll
        for (int q = 0; q < 8; ++q) {
            float4 v = src[q];
            w[m][4*q+0] = v.x; w[m][4*q+1] = v.y;
            w[m][4*q+2] = v.z; w[m][4*q+3] = v.w;
        }
        wih2[m][0] = Wih[(size_t)grow * IN_D + 2 * lane];
        wih2[m][1] = Wih[(size_t)grow * IN_D + 2 * lane + 1];
        breg[m]    = bih[grow] + bhh[grow];
    }

    float c = 0.0f;   // cell state (lane 0 of each wave)

    for (int t = 0; t < TSTEPS; ++t) {
        const int slot = (t - 1) & 1;   // consumed slot (valid when t > 0)

        // ---- W_ih @ x_t partial (no h dependency) ----
        const float2 xv = *(const float2*)(s0 + (size_t)t * IN_D + 2 * lane);
        float acc[4];
#pragma unroll
        for (int m = 0; m < 4; ++m)
            acc[m] = wih2[m][0] * xv.x + wih2[m][1] * xv.y;

        // ---- per-wave collective detect + stage: wave rg owns 128 pairs ----
        if (t > 0) {
            const u32 want = (u32)t;
            const u64* sp = pairs + (size_t)slot * NPAIRS + rg * 128 + 2 * lane;
            u64 q0 = __hip_atomic_load(sp,     __ATOMIC_RELAXED, __HIP_MEMORY_SCOPE_AGENT);
            u64 q1 = __hip_atomic_load(sp + 1, __ATOMIC_RELAXED, __HIP_MEMORY_SCOPE_AGENT);
            for (;;) {
                const int ok = ((u32)(q0 >> 32) == want) & ((u32)(q1 >> 32) == want);
                if (__all(ok)) break;
                q0 = __hip_atomic_load(sp,     __ATOMIC_RELAXED, __HIP_MEMORY_SCOPE_AGENT);
                q1 = __hip_atomic_load(sp + 1, __ATOMIC_RELAXED, __HIP_MEMORY_SCOPE_AGENT);
            }
            // unpack 2 pairs -> 4 f32, one b128 write, swizzled chunk
            float4 hv;
            hv.x = bf16_lo((u32)q0);
            hv.y = bf16_hi((u32)q0);
            hv.z = bf16_lo((u32)q1);
            hv.w = bf16_hi((u32)q1);
            const int cch = rg * 64 + lane;            // 16B chunk 0..511
            ldsH[slot][cch ^ ((cch >> 3) & 7)] = hv;
        }
        __syncthreads();   // sync1: ldsH staged

        // ---- recurrent matvec: 4 rows x 32 k per thread (f32, conflict-light) ----
        if (t > 0) {
#pragma unroll
            for (int j = 0; j < 8; ++j) {
                const int p = (8 * lane + j) ^ (lane & 7);
                float4 hv = ldsH[slot][p];
#pragma unroll
                for (int m = 0; m < 4; ++m) {
                    acc[m] += hv.x * w[m][4*j+0];
                    acc[m] += hv.y * w[m][4*j+1];
                    acc[m] += hv.z * w[m][4*j+2];
                    acc[m] += hv.w * w[m][4*j+3];
                }
            }
        }

        // ---- full 64-lane butterfly: all 4 gate sums complete at lane 0 ----
#pragma unroll
        for (int m = 0; m < 4; ++m) {
            acc[m] += __shfl_xor(acc[m], 1);
            acc[m] += __shfl_xor(acc[m], 2);
            acc[m] += __shfl_xor(acc[m], 4);
            acc[m] += __shfl_xor(acc[m], 8);
            acc[m] += __shfl_xor(acc[m], 16);
            acc[m] += __shfl_xor(acc[m], 32);
        }

        // ---- in-wave cell update (parallel across 8 waves, pre-sync2) ----
        if (lane == 0) {
            const float ig = fast_sig (acc[0] + breg[0]);
            const float fg = fast_sig (acc[1] + breg[1]);
            const float gg = fast_tanh(acc[2] + breg[2]);
            const float og = fast_sig (acc[3] + breg[3]);
            c = fg * c + ig * gg;
            const float h = og * fast_tanh(c);
            cellbuf[rg] = ((u64)bf16_rne(h) << 32) | (u64)__float_as_uint(h);
        }
        __syncthreads();   // sync2: cellbuf ready

        // ---- pack + publish (threads 0..3 of wave 0; 32B bursts only) ----
        if (tid < 4) {
            const u64 cb0 = cellbuf[2 * tid];
            const u64 cb1 = cellbuf[2 * tid + 1];
            const u64 pair = (((u64)(u32)(t + 1)) << 32)
                           | (u64)(((u32)(cb0 >> 32)) | (((u32)(cb1 >> 32)) << 16));
            __hip_atomic_store(&pairs[(size_t)(t & 1) * NPAIRS + wg * 4 + tid], pair,
                               __ATOMIC_RELAXED, __HIP_MEMORY_SCOPE_AGENT);
            // f32 record for out_head: 4 lanes x float2 = 32B coalesced
            *(float2*)&hs_out[(size_t)t * HID + hbase + 2 * tid] =
                make_float2(__uint_as_float((u32)cb0), __uint_as_float((u32)cb1));
        }
    }
}

// ---------------------------------------------------------------------------
// Output head: mu/logvar GEMV + sample + logprob. Block = 4 timesteps.
// ---------------------------------------------------------------------------
__global__ __launch_bounds__(256)
void out_head(const float* __restrict__ eps,
              const float* __restrict__ Wmu,
              const float* __restrict__ bmu,
              const float* __restrict__ Wlv,
              const float* __restrict__ blv,
              const float* __restrict__ hs,
              float* __restrict__ xs,
              float* __restrict__ lp)
{
    __shared__ __align__(16) float hlds[4][HID];
    __shared__ __align__(16) float exch[4][256];

    const int tid = threadIdx.x;
    const int t0  = blockIdx.x * 4;

    {
        const float4* src = (const float4*)(hs + (size_t)t0 * HID);
        float4* dst = (float4*)&hlds[0][0];
#pragma unroll
        for (int i = 0; i < 8; ++i)
            dst[tid + i * 256] = src[tid + i * 256];
    }
    __syncthreads();

    const int  jrow  = tid & 127;
    const bool is_lv = tid >= 128;
    const float* Wrow = (is_lv ? Wlv : Wmu) + (size_t)jrow * HID;
    const float  bias = is_lv ? blv[jrow] : bmu[jrow];

    float acc[4] = {0.f, 0.f, 0.f, 0.f};
    const float4* w4 = (const float4*)Wrow;
#pragma unroll 4
    for (int kq = 0; kq < HID / 4; ++kq) {
        float4 wv = w4[kq];
#pragma unroll
        for (int tt = 0; tt < 4; ++tt) {
            float4 hv = ((const float4*)&hlds[tt][0])[kq];
            acc[tt] += wv.x * hv.x + wv.y * hv.y + wv.z * hv.z + wv.w * hv.w;
        }
    }
#pragma unroll
    for (int tt = 0; tt < 4; ++tt) exch[tt][tid] = acc[tt] + bias;
    __syncthreads();

#pragma unroll
    for (int r = 0; r < 2; ++r) {
        const int item = tid + r * 256;
        const int tt = item >> 7;
        const int jj = item & 127;
        const int t  = t0 + tt;
        const float mu = exch[tt][jj];
        const float lv = exch[tt][128 + jj];
        const float e  = eps[(size_t)t * OUT_D + jj];
        const float sd = expf(0.5f * lv);
        const float x  = mu + sd * e;
        const float d  = (x - mu) / sd;
        const float l  = -0.5f * d * d - 0.5f * lv - 0.5f * LOG2PI_F;
        xs[(size_t)t * OUT_D + jj] = x;
        lp[(size_t)t * OUT_D + jj] = l;
    }
}

// ---------------------------------------------------------------------------
extern "C" void kernel_launch(void* const* d_in, const int* in_sizes, int n_in,
                              void* d_out, int out_size, void* d_ws, size_t ws_size,
                              hipStream_t stream)
{
    (void)in_sizes; (void)n_in; (void)out_size; (void)ws_size;

    const float* s0  = (const float*)d_in[0];
    const float* eps = (const float*)d_in[1];
    const float* Wih = (const float*)d_in[2];
    const float* Whh = (const float*)d_in[3];
    const float* bih = (const float*)d_in[4];
    const float* bhh = (const float*)d_in[5];
    const float* Wmu = (const float*)d_in[6];
    const float* bmu = (const float*)d_in[7];
    const float* Wlv = (const float*)d_in[8];
    const float* blv = (const float*)d_in[9];

    float* out = (float*)d_out;
    float* xs = out;                         // [1024][128]
    float* lp = out + TSTEPS * OUT_D;        // [1024][128]
    float* hs = out + 2 * TSTEPS * OUT_D;    // [1024][2048]

    u64* pairs = (u64*)d_ws;                 // [2][1024] x 8B = 16KB

    // zero tags each launch (tag 0 matches no wanted tag >= 1)
    (void)hipMemsetAsync(d_ws, 0, 2 * NPAIRS * sizeof(u64), stream);

    hipLaunchKernelGGL(lstm_persist, dim3(NWG), dim3(NTHR), 0, stream,
                       s0, Wih, Whh, bih, bhh, hs, pairs);

    hipLaunchKernelGGL(out_head, dim3(TSTEPS / 4), dim3(256), 0, stream,
                       eps, Wmu, bmu, Wlv, blv, hs, xs, lp);
}